// Round 1
// baseline (4742.722 us; speedup 1.0000x reference)
//
#include <hip/hip_runtime.h>

#define KNN 10
constexpr int N = 2048;
constexpr int M = 131072;
constexpr int D = 256;
constexpr int C = 126;

constexpr int BN = 128;          // query rows per block
constexpr int BM = 128;          // bank rows per subtile
constexpr int KC = 16;           // k-slice staged in LDS
constexpr int NSUB = 8;          // subtiles per block -> 1024 m per block
constexpr int NCHUNK = M / (BM * NSUB);     // 128 chunks
constexpr int CAND_PER_N = NCHUNK * KNN;    // 1280 candidates per query

// ---------------- phase 0: bank row squared norms ----------------
__global__ __launch_bounds__(256) void b2_kernel(const float* __restrict__ bank,
                                                 float* __restrict__ b2) {
  const int wave = threadIdx.x >> 6, lane = threadIdx.x & 63;
  const int m = (blockIdx.x << 2) + wave;          // 4 rows per block
  const float4 v = ((const float4*)(bank + (size_t)m * D))[lane];  // 64*4 = 256
  float s = v.x * v.x + v.y * v.y + v.z * v.z + v.w * v.w;
#pragma unroll
  for (int off = 32; off >= 1; off >>= 1) s += __shfl_down(s, off);
  if (lane == 0) b2[m] = s;
}

// ---------------- phase 1: fused SGEMM + per-chunk top-10 ----------------
// score[n][m] = b2[m] - 2*dot(features[n], bank[m])  (rank-equivalent to dist)
__global__ __launch_bounds__(256) void knn_chunk_kernel(
    const float* __restrict__ Ag, const float* __restrict__ Bg,
    const float* __restrict__ b2g, float* __restrict__ cand_s,
    int* __restrict__ cand_i) {
  // LDS: As[KC][BN+4] | Bs[KC][BM+4] | S64[64][129]  = 49,920 B total
  __shared__ float smem[KC * (BN + 4) + KC * (BM + 4) + 64 * 129];
  float (*As)[BN + 4] = (float(*)[BN + 4])smem;
  float (*Bs)[BM + 4] = (float(*)[BM + 4])(smem + KC * (BN + 4));
  float (*S64)[129]   = (float(*)[129])(smem + KC * (BN + 4) + KC * (BM + 4));

  const int tid = threadIdx.x;
  const int tx = tid & 15, ty = tid >> 4;          // 16x16 thread grid
  const int n0 = blockIdx.y * BN;
  const int chunk = blockIdx.x;

  // persistent per-(row,half) top-10, ascending (ts[9] = current cutoff)
  float ts[KNN];
  int ti[KNN];
#pragma unroll
  for (int q = 0; q < KNN; ++q) { ts[q] = 3.0e38f; ti[q] = -1; }

  for (int sub = 0; sub < NSUB; ++sub) {
    const int m0 = (chunk * NSUB + sub) * BM;
    float acc[8][8];
#pragma unroll
    for (int i = 0; i < 8; ++i)
#pragma unroll
      for (int j = 0; j < 8; ++j) acc[i][j] = 0.0f;

    for (int k0 = 0; k0 < D; k0 += KC) {
      __syncthreads();
      // stage A and B k-slices (k-major so micro-tile loads vectorize)
#pragma unroll
      for (int r = 0; r < 2; ++r) {
        const int id = tid + (r << 8);             // 0..511
        const int n = id >> 2, kk = (id & 3) << 2; // row, k offset (float4)
        const float4 va = *(const float4*)(Ag + (size_t)(n0 + n) * D + k0 + kk);
        As[kk + 0][n] = va.x; As[kk + 1][n] = va.y;
        As[kk + 2][n] = va.z; As[kk + 3][n] = va.w;
        const float4 vb = *(const float4*)(Bg + (size_t)(m0 + n) * D + k0 + kk);
        Bs[kk + 0][n] = vb.x; Bs[kk + 1][n] = vb.y;
        Bs[kk + 2][n] = vb.z; Bs[kk + 3][n] = vb.w;
      }
      __syncthreads();
#pragma unroll
      for (int kk = 0; kk < KC; ++kk) {
        const float4 a0 = *(const float4*)&As[kk][ty << 3];
        const float4 a1 = *(const float4*)&As[kk][(ty << 3) + 4];
        const float4 b0 = *(const float4*)&Bs[kk][tx << 3];
        const float4 b1 = *(const float4*)&Bs[kk][(tx << 3) + 4];
        const float av[8] = {a0.x, a0.y, a0.z, a0.w, a1.x, a1.y, a1.z, a1.w};
        const float bv[8] = {b0.x, b0.y, b0.z, b0.w, b1.x, b1.y, b1.z, b1.w};
#pragma unroll
        for (int i = 0; i < 8; ++i)
#pragma unroll
          for (int j = 0; j < 8; ++j) acc[i][j] = fmaf(av[i], bv[j], acc[i][j]);
      }
    }

    float bb[8];
#pragma unroll
    for (int j = 0; j < 8; ++j) bb[j] = b2g[m0 + (tx << 3) + j];

    // two passes: rows 0..63 then 64..127 through the 64x129 score tile
    for (int p = 0; p < 2; ++p) {
      __syncthreads();
      if ((ty >> 3) == p) {
#pragma unroll
        for (int i = 0; i < 8; ++i)
#pragma unroll
          for (int jj = 0; jj < 8; ++jj) {
            const int j = (jj + ty) & 7;  // rotate j by ty -> 4-way banks max
            S64[((ty & 7) << 3) + i][(tx << 3) + j] = fmaf(-2.0f, acc[i][j], bb[j]);
          }
      }
      __syncthreads();
      const int r = tid & 127;
      if ((r >> 6) == p) {               // wave-uniform (waves 0,2 / 1,3)
        const int lr = r & 63;
        const int cbase = (tid >> 7) << 6;  // half-row per scanner
        for (int c = 0; c < 64; ++c) {
          const float s = S64[lr][cbase + c];
          if (s < ts[KNN - 1]) {
            float cs = s;
            int ci = m0 + cbase + c;
#pragma unroll
            for (int q = 0; q < KNN; ++q) {
              if (cs < ts[q]) {
                const float tf = ts[q]; ts[q] = cs; cs = tf;
                const int tv = ti[q]; ti[q] = ci; ci = tv;
              }
            }
          }
        }
      }
    }
  }

  // merge the two half-row scanners, write 10 candidates per row
  __syncthreads();
  const int r = tid & 127, h = tid >> 7;
  float* mg = (float*)S64;
  if (h == 1) {
#pragma unroll
    for (int q = 0; q < KNN; ++q) {
      mg[r * 20 + q] = ts[q];
      ((int*)mg)[r * 20 + 10 + q] = ti[q];
    }
  }
  __syncthreads();
  if (h == 0) {
#pragma unroll
    for (int q = 0; q < KNN; ++q) {
      const float s = mg[r * 20 + q];
      const int idx = ((int*)mg)[r * 20 + 10 + q];
      if (s < ts[KNN - 1]) {
        float cs = s;
        int ci = idx;
#pragma unroll
        for (int u = 0; u < KNN; ++u) {
          if (cs < ts[u]) {
            const float tf = ts[u]; ts[u] = cs; cs = tf;
            const int tv = ti[u]; ti[u] = ci; ci = tv;
          }
        }
      }
    }
    const size_t base = ((size_t)(n0 + r) * NCHUNK + chunk) * KNN;
#pragma unroll
    for (int q = 0; q < KNN; ++q) {
      cand_s[base + q] = ts[q];
      cand_i[base + q] = ti[q];
    }
  }
}

// ---------------- phase 2: global top-10 merge + probs mean + argmax ----------------
__global__ __launch_bounds__(256) void knn_finalize_kernel(
    const float* __restrict__ cand_s, const int* __restrict__ cand_i,
    const float* __restrict__ probs, float* __restrict__ out) {
  const int n = blockIdx.x, t = threadIdx.x;
  const size_t cb = (size_t)n * CAND_PER_N;

  float sc[5];
  int id_[5];
#pragma unroll
  for (int r = 0; r < 5; ++r) {
    sc[r] = cand_s[cb + t + (r << 8)];
    id_[r] = cand_i[cb + t + (r << 8)];
  }

  __shared__ float rs[4];
  __shared__ int rm[4];
  __shared__ int win[KNN];

  for (int round = 0; round < KNN; ++round) {
    float bs = 3.0e38f;
    int bm = 0x7fffffff;
#pragma unroll
    for (int r = 0; r < 5; ++r) {
      const bool better =
          (id_[r] >= 0) && (sc[r] < bs || (sc[r] == bs && id_[r] < bm));
      if (better) { bs = sc[r]; bm = id_[r]; }
    }
#pragma unroll
    for (int off = 32; off >= 1; off >>= 1) {
      const float os = __shfl_down(bs, off);
      const int om = __shfl_down(bm, off);
      if (os < bs || (os == bs && om < bm)) { bs = os; bm = om; }
    }
    if ((t & 63) == 0) { rs[t >> 6] = bs; rm[t >> 6] = bm; }
    __syncthreads();
    if (t == 0) {
      for (int w = 1; w < 4; ++w)
        if (rs[w] < bs || (rs[w] == bs && rm[w] < bm)) { bs = rs[w]; bm = rm[w]; }
      // t==0's own bs/bm came through rs[0]/rm[0] path too
      float fb = rs[0]; int fm = rm[0];
      for (int w = 1; w < 4; ++w)
        if (rs[w] < fb || (rs[w] == fb && rm[w] < fm)) { fb = rs[w]; fm = rm[w]; }
      win[round] = fm;
    }
    __syncthreads();
    const int wmv = win[round];
#pragma unroll
    for (int r = 0; r < 5; ++r)
      if (id_[r] == wmv) id_[r] = -1;  // m indices are globally unique
  }

  // probs mean over the 10 winners; lane t = class index (coalesced)
  __shared__ float pv[128];
  float myp = -1.0e30f;
  if (t < C) {
    float acc = 0.0f;
#pragma unroll
    for (int q = 0; q < KNN; ++q) acc += probs[(size_t)win[q] * C + t];
    myp = acc * (1.0f / KNN);
    out[N + (size_t)n * C + t] = myp;
  }
  if (t < 128) pv[t] = myp;
  __syncthreads();
  if (t == 0) {
    float bv = pv[0];
    int bi = 0;
    for (int c = 1; c < C; ++c)
      if (pv[c] > bv) { bv = pv[c]; bi = c; }  // first-index tie-break
    out[n] = (float)bi;                        // labels as float32
  }
}

extern "C" void kernel_launch(void* const* d_in, const int* in_sizes, int n_in,
                              void* d_out, int out_size, void* d_ws, size_t ws_size,
                              hipStream_t stream) {
  const float* features = (const float*)d_in[0];  // (N, D)
  const float* bank = (const float*)d_in[1];      // (M, D)
  const float* probs = (const float*)d_in[2];     // (M, C)
  float* out = (float*)d_out;                     // [labels(N) | probs(N*C)]

  float* b2 = (float*)d_ws;                       // M floats
  float* cand_s = b2 + M;                         // N*1280 floats
  int* cand_i = (int*)(cand_s + (size_t)N * CAND_PER_N);  // N*1280 ints (~21.5 MB total)

  b2_kernel<<<M / 4, 256, 0, stream>>>(bank, b2);
  knn_chunk_kernel<<<dim3(NCHUNK, N / BN), 256, 0, stream>>>(features, bank, b2,
                                                             cand_s, cand_i);
  knn_finalize_kernel<<<N, 256, 0, stream>>>(cand_s, cand_i, probs, out);
}

// Round 3
// 2403.307 us; speedup vs baseline: 1.9734x; 1.9734x over previous
//
#include <hip/hip_runtime.h>

#define KNN 10
constexpr int N = 2048;
constexpr int M = 131072;
constexpr int D = 256;
constexpr int C = 126;

constexpr int BN = 128;          // query rows per block
constexpr int BM = 128;          // bank rows per subtile
constexpr int BK = 32;           // k-slice per stage (one MFMA K)
constexpr int NSUB = 8;          // subtiles per block -> 1024 m per block
constexpr int NCHUNK = M / (BM * NSUB);     // 128 chunks
constexpr int CAND_PER_N = NCHUNK * KNN;    // 1280 candidates per query

typedef __fp16   half2v __attribute__((ext_vector_type(2)));  // cvt_pkrtz result type
typedef _Float16 half8  __attribute__((ext_vector_type(8)));  // MFMA operand type
typedef float   float4v __attribute__((ext_vector_type(4)));

// ---------------- phase 0: bank row squared norms ----------------
__global__ __launch_bounds__(256) void b2_kernel(const float* __restrict__ bank,
                                                 float* __restrict__ b2) {
  const int wave = threadIdx.x >> 6, lane = threadIdx.x & 63;
  const int m = (blockIdx.x << 2) + wave;          // 4 rows per block
  const float4 v = ((const float4*)(bank + (size_t)m * D))[lane];  // 64*4 = 256
  float s = v.x * v.x + v.y * v.y + v.z * v.z + v.w * v.w;
#pragma unroll
  for (int off = 32; off >= 1; off >>= 1) s += __shfl_down(s, off);
  if (lane == 0) b2[m] = s;
}

// ---------------- phase 1: MFMA fp16-split GEMM + per-chunk top-10 ----------------
// score[n][m] = b2[m] - 2*dot(features[n], bank[m])  (rank-equivalent to dist)
// LDS staging images are MFMA-native: fragment = 64 lanes x 16 B contiguous,
// lane holds A[row=lane&15][k=(lane>>4)*8 + j] (16x16x32 f16 A/B layout).
__global__ __launch_bounds__(256, 2) void knn_chunk_kernel(
    const float* __restrict__ Ag, const float* __restrict__ Bg,
    const float* __restrict__ b2g, float* __restrict__ cand_s,
    int* __restrict__ cand_i) {
  // staging: Ah[0,8K) Al[8K,16K) Bh[16K,24K) Bl[24K,32K); score tile 64x130 fp32
  __shared__ float smem[64 * 130];   // 33280 B
  char* lds = (char*)smem;
  float (*S64)[130] = (float(*)[130])smem;

  const int tid = threadIdx.x;
  const int lane = tid & 63;
  const int wave = tid >> 6;
  const int wx = wave & 1, wy = wave >> 1;   // 2x2 wave grid, 64x64 per wave
  const int n0 = blockIdx.y * BN;
  const int chunk = blockIdx.x;

  // persistent per-(row, col-half) top-10, ascending (ts[9] = cutoff)
  float ts[KNN];
  int ti_[KNN];
#pragma unroll
  for (int q = 0; q < KNN; ++q) { ts[q] = 3.0e38f; ti_[q] = -1; }

  for (int sub = 0; sub < NSUB; ++sub) {
    const int m0 = (chunk * NSUB + sub) * BM;
    float4v acc[4][4];
#pragma unroll
    for (int i = 0; i < 4; ++i)
#pragma unroll
      for (int j = 0; j < 4; ++j) acc[i][j] = (float4v)(0.0f);

    for (int k0 = 0; k0 < D; k0 += BK) {
      __syncthreads();
      // stage A and B 128x32 fp32 -> fp16 hi/lo MFMA images
#pragma unroll
      for (int r = 0; r < 4; ++r) {
        const int id = tid + (r << 8);   // 0..1023
        const int n = id >> 3;           // 0..127
        const int c4 = id & 7;           // float4 within row, k = c4*4
        const int k = c4 << 2;
        const int off = ((n >> 4) << 10) + (((n & 15) | ((k >> 3) << 4)) << 4) +
                        ((c4 & 1) << 3);
        {
          const float4 v = *(const float4*)(Ag + (size_t)(n0 + n) * D + k0 + k);
          const half2v h01 = __builtin_amdgcn_cvt_pkrtz(v.x, v.y);
          const half2v h23 = __builtin_amdgcn_cvt_pkrtz(v.z, v.w);
          const half2v l01 =
              __builtin_amdgcn_cvt_pkrtz(v.x - (float)h01.x, v.y - (float)h01.y);
          const half2v l23 =
              __builtin_amdgcn_cvt_pkrtz(v.z - (float)h23.x, v.w - (float)h23.y);
          union { half2v h[2]; uint2 u; } hh, ll;
          hh.h[0] = h01; hh.h[1] = h23;
          ll.h[0] = l01; ll.h[1] = l23;
          *(uint2*)(lds + off) = hh.u;
          *(uint2*)(lds + 8192 + off) = ll.u;
        }
        {
          const float4 v = *(const float4*)(Bg + (size_t)(m0 + n) * D + k0 + k);
          const half2v h01 = __builtin_amdgcn_cvt_pkrtz(v.x, v.y);
          const half2v h23 = __builtin_amdgcn_cvt_pkrtz(v.z, v.w);
          const half2v l01 =
              __builtin_amdgcn_cvt_pkrtz(v.x - (float)h01.x, v.y - (float)h01.y);
          const half2v l23 =
              __builtin_amdgcn_cvt_pkrtz(v.z - (float)h23.x, v.w - (float)h23.y);
          union { half2v h[2]; uint2 u; } hh, ll;
          hh.h[0] = h01; hh.h[1] = h23;
          ll.h[0] = l01; ll.h[1] = l23;
          *(uint2*)(lds + 16384 + off) = hh.u;
          *(uint2*)(lds + 24576 + off) = ll.u;
        }
      }
      __syncthreads();
      // conflict-free fragment reads (lane*16 contiguous)
      half8 ah[4], al[4], bh[4], bl[4];
#pragma unroll
      for (int t = 0; t < 4; ++t) {
        const int ao = ((((wy << 2) + t) << 10)) + (lane << 4);
        ah[t] = *(half8*)(lds + ao);
        al[t] = *(half8*)(lds + 8192 + ao);
        const int bo = ((((wx << 2) + t) << 10)) + (lane << 4);
        bh[t] = *(half8*)(lds + 16384 + bo);
        bl[t] = *(half8*)(lds + 24576 + bo);
      }
#pragma unroll
      for (int i = 0; i < 4; ++i)
#pragma unroll
        for (int j = 0; j < 4; ++j) {
          acc[i][j] = __builtin_amdgcn_mfma_f32_16x16x32_f16(ah[i], bh[j], acc[i][j], 0, 0, 0);
          acc[i][j] = __builtin_amdgcn_mfma_f32_16x16x32_f16(ah[i], bl[j], acc[i][j], 0, 0, 0);
          acc[i][j] = __builtin_amdgcn_mfma_f32_16x16x32_f16(al[i], bh[j], acc[i][j], 0, 0, 0);
        }
    }

    float b2v[4];
#pragma unroll
    for (int j = 0; j < 4; ++j)
      b2v[j] = b2g[m0 + (wx << 6) + (j << 4) + (lane & 15)];

    // two passes: score rows 0..63 (waves wy==0) then 64..127 (wy==1)
    for (int p = 0; p < 2; ++p) {
      __syncthreads();
      if (wy == p) {
        // C/D layout: col=lane&15, row=(lane>>4)*4+reg  [m89]
#pragma unroll
        for (int i = 0; i < 4; ++i)
#pragma unroll
          for (int j = 0; j < 4; ++j)
#pragma unroll
            for (int r = 0; r < 4; ++r)
              S64[(i << 4) + ((lane >> 4) << 2) + r]
                 [(wx << 6) + (j << 4) + (lane & 15)] =
                  fmaf(-2.0f, acc[i][j][r], b2v[j]);
      }
      __syncthreads();
      const int rr = tid & 127;
      if ((rr >> 6) == p) {               // wave-uniform (waves 0,2 / 1,3)
        const int lr = rr & 63;
        const int cbase = (tid >> 7) << 6;  // half-row per scanner
        float cut = ts[KNN - 1];
        for (int c = 0; c < 64; ++c) {
          const float s = S64[lr][cbase + c];
          if (s < cut) {
            float cs = s;
            int ci = m0 + cbase + c;
#pragma unroll
            for (int q = 0; q < KNN; ++q) {
              if (cs < ts[q]) {
                const float tf = ts[q]; ts[q] = cs; cs = tf;
                const int tv = ti_[q]; ti_[q] = ci; ci = tv;
              }
            }
            cut = ts[KNN - 1];
          }
        }
      }
    }
  }

  // merge the two half-row scanners, write 10 candidates per row
  __syncthreads();
  const int r = tid & 127, h = tid >> 7;
  float* mg = (float*)smem;
  if (h == 1) {
#pragma unroll
    for (int q = 0; q < KNN; ++q) {
      mg[r * 20 + q] = ts[q];
      ((int*)mg)[r * 20 + 10 + q] = ti_[q];
    }
  }
  __syncthreads();
  if (h == 0) {
#pragma unroll
    for (int q = 0; q < KNN; ++q) {
      const float s = mg[r * 20 + q];
      const int idx = ((int*)mg)[r * 20 + 10 + q];
      if (s < ts[KNN - 1]) {
        float cs = s;
        int ci = idx;
#pragma unroll
        for (int u = 0; u < KNN; ++u) {
          if (cs < ts[u]) {
            const float tf = ts[u]; ts[u] = cs; cs = tf;
            const int tv = ti_[u]; ti_[u] = ci; ci = tv;
          }
        }
      }
    }
    const size_t base = ((size_t)(n0 + r) * NCHUNK + chunk) * KNN;
#pragma unroll
    for (int q = 0; q < KNN; ++q) {
      cand_s[base + q] = ts[q];
      cand_i[base + q] = ti_[q];
    }
  }
}

// ---------------- phase 2: global top-10 merge + probs mean + argmax ----------------
__global__ __launch_bounds__(256) void knn_finalize_kernel(
    const float* __restrict__ cand_s, const int* __restrict__ cand_i,
    const float* __restrict__ probs, float* __restrict__ out) {
  const int n = blockIdx.x, t = threadIdx.x;
  const size_t cb = (size_t)n * CAND_PER_N;

  float sc[5];
  int id_[5];
#pragma unroll
  for (int r = 0; r < 5; ++r) {
    sc[r] = cand_s[cb + t + (r << 8)];
    id_[r] = cand_i[cb + t + (r << 8)];
  }

  __shared__ float rs[4];
  __shared__ int rm[4];
  __shared__ int win[KNN];

  for (int round = 0; round < KNN; ++round) {
    float bs = 3.0e38f;
    int bm = 0x7fffffff;
#pragma unroll
    for (int r = 0; r < 5; ++r) {
      const bool better =
          (id_[r] >= 0) && (sc[r] < bs || (sc[r] == bs && id_[r] < bm));
      if (better) { bs = sc[r]; bm = id_[r]; }
    }
#pragma unroll
    for (int off = 32; off >= 1; off >>= 1) {
      const float os = __shfl_down(bs, off);
      const int om = __shfl_down(bm, off);
      if (os < bs || (os == bs && om < bm)) { bs = os; bm = om; }
    }
    if ((t & 63) == 0) { rs[t >> 6] = bs; rm[t >> 6] = bm; }
    __syncthreads();
    if (t == 0) {
      float fb = rs[0]; int fm = rm[0];
      for (int w = 1; w < 4; ++w)
        if (rs[w] < fb || (rs[w] == fb && rm[w] < fm)) { fb = rs[w]; fm = rm[w]; }
      win[round] = fm;
    }
    __syncthreads();
    const int wmv = win[round];
#pragma unroll
    for (int r = 0; r < 5; ++r)
      if (id_[r] == wmv) id_[r] = -1;  // m indices are globally unique
  }

  // probs mean over the 10 winners; lane t = class index (coalesced)
  __shared__ float pv[128];
  float myp = -1.0e30f;
  if (t < C) {
    float acc = 0.0f;
#pragma unroll
    for (int q = 0; q < KNN; ++q) acc += probs[(size_t)win[q] * C + t];
    myp = acc * (1.0f / KNN);
    out[N + (size_t)n * C + t] = myp;
  }
  if (t < 128) pv[t] = myp;
  __syncthreads();
  if (t == 0) {
    float bv = pv[0];
    int bi = 0;
    for (int c = 1; c < C; ++c)
      if (pv[c] > bv) { bv = pv[c]; bi = c; }  // first-index tie-break
    out[n] = (float)bi;                        // labels as float32
  }
}

extern "C" void kernel_launch(void* const* d_in, const int* in_sizes, int n_in,
                              void* d_out, int out_size, void* d_ws, size_t ws_size,
                              hipStream_t stream) {
  const float* features = (const float*)d_in[0];  // (N, D)
  const float* bank = (const float*)d_in[1];      // (M, D)
  const float* probs = (const float*)d_in[2];     // (M, C)
  float* out = (float*)d_out;                     // [labels(N) | probs(N*C)]

  float* b2 = (float*)d_ws;                       // M floats
  float* cand_s = b2 + M;                         // N*1280 floats
  int* cand_i = (int*)(cand_s + (size_t)N * CAND_PER_N);  // N*1280 ints (~21.5 MB)

  b2_kernel<<<M / 4, 256, 0, stream>>>(bank, b2);
  knn_chunk_kernel<<<dim3(NCHUNK, N / BN), 256, 0, stream>>>(features, bank, b2,
                                                             cand_s, cand_i);
  knn_finalize_kernel<<<N, 256, 0, stream>>>(cand_s, cand_i, probs, out);
}

// Round 4
// 1409.659 us; speedup vs baseline: 3.3644x; 1.7049x over previous
//
#include <hip/hip_runtime.h>

#define KNN 10
constexpr int N = 2048;
constexpr int M = 131072;
constexpr int D = 256;
constexpr int C = 126;

constexpr int BN = 128;          // query rows per block
constexpr int BM = 128;          // bank rows per subtile
constexpr int BK = 32;           // k-slice per stage (one MFMA K)
constexpr int NSUB = 8;          // subtiles per block -> 1024 m per block
constexpr int NCHUNK = M / (BM * NSUB);     // 128 chunks
constexpr int CAND_PER_N = NCHUNK * KNN;    // 1280 candidates per query
constexpr int KSEG = D / 32;                // 8 k-segments per row-group

typedef __fp16   half2v __attribute__((ext_vector_type(2)));  // cvt_pkrtz result type
typedef _Float16 half8  __attribute__((ext_vector_type(8)));  // MFMA operand type
typedef float   float4v __attribute__((ext_vector_type(4)));

typedef const __attribute__((address_space(1))) void* gas_p;
typedef __attribute__((address_space(3))) void* las_p;

__device__ __forceinline__ void gload_lds16(const void* g, void* l) {
  __builtin_amdgcn_global_load_lds((gas_p)g, (las_p)l, 16, 0, 0);
}

// ---------------- phase 0: bank row squared norms ----------------
__global__ __launch_bounds__(256) void b2_kernel(const float* __restrict__ bank,
                                                 float* __restrict__ b2) {
  const int wave = threadIdx.x >> 6, lane = threadIdx.x & 63;
  const int m = (blockIdx.x << 2) + wave;          // 4 rows per block
  const float4 v = ((const float4*)(bank + (size_t)m * D))[lane];  // 64*4 = 256
  float s = v.x * v.x + v.y * v.y + v.z * v.z + v.w * v.w;
#pragma unroll
  for (int off = 32; off >= 1; off >>= 1) s += __shfl_down(s, off);
  if (lane == 0) b2[m] = s;
}

// ---------------- phase 0b: fp32 -> fp16 hi/lo images, MFMA-fragment layout ----
// Image layout: seg = (m/16)*KSEG + (k/32); within seg, lane slot
// (m&15) | ((k>>3)&3)<<4 holds 8 halves (16 B) of k%8. One seg = 1024 B.
__global__ __launch_bounds__(256) void cvt_kernel(const float* __restrict__ src,
                                                  char* __restrict__ hi,
                                                  char* __restrict__ lo) {
  const int gid = blockIdx.x * 256 + threadIdx.x;
  const int m = gid >> 5, kg = gid & 31;           // kg: 8-element k-group
  const float4 v0 = *(const float4*)(src + (size_t)m * D + (kg << 3));
  const float4 v1 = *(const float4*)(src + (size_t)m * D + (kg << 3) + 4);
  union Pack { half2v h[4]; uint4 u; };
  Pack hh, ll;
  hh.h[0] = __builtin_amdgcn_cvt_pkrtz(v0.x, v0.y);
  hh.h[1] = __builtin_amdgcn_cvt_pkrtz(v0.z, v0.w);
  hh.h[2] = __builtin_amdgcn_cvt_pkrtz(v1.x, v1.y);
  hh.h[3] = __builtin_amdgcn_cvt_pkrtz(v1.z, v1.w);
  ll.h[0] = __builtin_amdgcn_cvt_pkrtz(v0.x - (float)hh.h[0].x, v0.y - (float)hh.h[0].y);
  ll.h[1] = __builtin_amdgcn_cvt_pkrtz(v0.z - (float)hh.h[1].x, v0.w - (float)hh.h[1].y);
  ll.h[2] = __builtin_amdgcn_cvt_pkrtz(v1.x - (float)hh.h[2].x, v1.y - (float)hh.h[2].y);
  ll.h[3] = __builtin_amdgcn_cvt_pkrtz(v1.z - (float)hh.h[3].x, v1.w - (float)hh.h[3].y);
  const size_t off = (((size_t)(m >> 4) * KSEG + (kg >> 2)) << 10) +
                     (((m & 15) | ((kg & 3) << 4)) << 4);
  *(uint4*)(hi + off) = hh.u;
  *(uint4*)(lo + off) = ll.u;
}

// ---------------- phase 1 (fast): DMA-staged MFMA GEMM + per-chunk top-10 ------
__global__ __launch_bounds__(256, 3) void knn_chunk_mfma(
    const char* __restrict__ pAhi, const char* __restrict__ pAlo,
    const char* __restrict__ pBhi, const char* __restrict__ pBlo,
    const float* __restrict__ b2g, float* __restrict__ cand_s,
    int* __restrict__ cand_i) {
  // staging: Ah[0,8K) Al[8K,16K) Bh[16K,24K) Bl[24K,32K); score tile 64x130 fp32
  __shared__ float smem[64 * 130];   // 33280 B
  char* lds = (char*)smem;
  float (*S64)[130] = (float(*)[130])smem;

  const int tid = threadIdx.x;
  const int lane = tid & 63;
  const int wave = tid >> 6;
  const int wx = wave & 1, wy = wave >> 1;   // 2x2 wave grid, 64x64 per wave
  const int n0 = blockIdx.y * BN;
  const int chunk = blockIdx.x;
  const int ag0 = n0 >> 4;                   // A row-group base

  float ts[KNN];
  int ti_[KNN];
#pragma unroll
  for (int q = 0; q < KNN; ++q) { ts[q] = 3.0e38f; ti_[q] = -1; }

  for (int sub = 0; sub < NSUB; ++sub) {
    const int m0 = (chunk * NSUB + sub) * BM;
    const int bg0 = m0 >> 4;
    float4v acc[4][4];
#pragma unroll
    for (int i = 0; i < 4; ++i)
#pragma unroll
      for (int j = 0; j < 4; ++j) acc[i][j] = (float4v)(0.0f);

    for (int k0 = 0; k0 < D; k0 += BK) {
      const int kseg = k0 >> 5;
      __syncthreads();
      // DMA-stage A/B hi/lo fragments: 8 segs each, 2 per wave, 16 B/lane
#pragma unroll
      for (int t = 0; t < 2; ++t) {
        const int grp = (wave << 1) + t;     // 0..7
        const size_t aoff = (((size_t)(ag0 + grp) * KSEG + kseg) << 10) + (lane << 4);
        const size_t boff = (((size_t)(bg0 + grp) * KSEG + kseg) << 10) + (lane << 4);
        const int ldst = (grp << 10) + (lane << 4);
        gload_lds16(pAhi + aoff, lds + ldst);
        gload_lds16(pAlo + aoff, lds + 8192 + ldst);
        gload_lds16(pBhi + boff, lds + 16384 + ldst);
        gload_lds16(pBlo + boff, lds + 24576 + ldst);
      }
      __syncthreads();
      // conflict-free fragment reads (lane*16 contiguous)
      half8 ah[4], al[4], bh[4], bl[4];
#pragma unroll
      for (int t = 0; t < 4; ++t) {
        const int ao = ((((wy << 2) + t) << 10)) + (lane << 4);
        ah[t] = *(half8*)(lds + ao);
        al[t] = *(half8*)(lds + 8192 + ao);
        const int bo = ((((wx << 2) + t) << 10)) + (lane << 4);
        bh[t] = *(half8*)(lds + 16384 + bo);
        bl[t] = *(half8*)(lds + 24576 + bo);
      }
#pragma unroll
      for (int i = 0; i < 4; ++i)
#pragma unroll
        for (int j = 0; j < 4; ++j) {
          acc[i][j] = __builtin_amdgcn_mfma_f32_16x16x32_f16(ah[i], bh[j], acc[i][j], 0, 0, 0);
          acc[i][j] = __builtin_amdgcn_mfma_f32_16x16x32_f16(ah[i], bl[j], acc[i][j], 0, 0, 0);
          acc[i][j] = __builtin_amdgcn_mfma_f32_16x16x32_f16(al[i], bh[j], acc[i][j], 0, 0, 0);
        }
    }

    float b2v[4];
#pragma unroll
    for (int j = 0; j < 4; ++j)
      b2v[j] = b2g[m0 + (wx << 6) + (j << 4) + (lane & 15)];

    // two passes: score rows 0..63 (waves wy==0) then 64..127 (wy==1)
    for (int p = 0; p < 2; ++p) {
      __syncthreads();
      if (wy == p) {
        // C/D layout: col=lane&15, row=(lane>>4)*4+reg  [m89]
#pragma unroll
        for (int i = 0; i < 4; ++i)
#pragma unroll
          for (int j = 0; j < 4; ++j)
#pragma unroll
            for (int r = 0; r < 4; ++r)
              S64[(i << 4) + ((lane >> 4) << 2) + r]
                 [(wx << 6) + (j << 4) + (lane & 15)] =
                  fmaf(-2.0f, acc[i][j][r], b2v[j]);
      }
      __syncthreads();
      const int rr = tid & 127;
      if ((rr >> 6) == p) {               // wave-uniform (waves 0,2 / 1,3)
        const int lr = rr & 63;
        const int cbase = (tid >> 7) << 6;  // half-row per scanner
        float cut = ts[KNN - 1];
        for (int c = 0; c < 64; ++c) {
          const float s = S64[lr][cbase + c];
          if (s < cut) {
            float cs = s;
            int ci = m0 + cbase + c;
#pragma unroll
            for (int q = 0; q < KNN; ++q) {
              if (cs < ts[q]) {
                const float tf = ts[q]; ts[q] = cs; cs = tf;
                const int tv = ti_[q]; ti_[q] = ci; ci = tv;
              }
            }
            cut = ts[KNN - 1];
          }
        }
      }
    }
  }

  // merge the two half-row scanners, write 10 candidates per row
  __syncthreads();
  const int r = tid & 127, h = tid >> 7;
  float* mg = (float*)smem;
  if (h == 1) {
#pragma unroll
    for (int q = 0; q < KNN; ++q) {
      mg[r * 20 + q] = ts[q];
      ((int*)mg)[r * 20 + 10 + q] = ti_[q];
    }
  }
  __syncthreads();
  if (h == 0) {
#pragma unroll
    for (int q = 0; q < KNN; ++q) {
      const float s = mg[r * 20 + q];
      const int idx = ((int*)mg)[r * 20 + 10 + q];
      if (s < ts[KNN - 1]) {
        float cs = s;
        int ci = idx;
#pragma unroll
        for (int u = 0; u < KNN; ++u) {
          if (cs < ts[u]) {
            const float tf = ts[u]; ts[u] = cs; cs = tf;
            const int tv = ti_[u]; ti_[u] = ci; ci = tv;
          }
        }
      }
    }
    const size_t base = ((size_t)(n0 + r) * NCHUNK + chunk) * KNN;
#pragma unroll
    for (int q = 0; q < KNN; ++q) {
      cand_s[base + q] = ts[q];
      cand_i[base + q] = ti_[q];
    }
  }
}

// ---------------- phase 1 (fallback, round-3 proven): in-kernel conversion ----
__global__ __launch_bounds__(256, 2) void knn_chunk_fallback(
    const float* __restrict__ Ag, const float* __restrict__ Bg,
    const float* __restrict__ b2g, float* __restrict__ cand_s,
    int* __restrict__ cand_i) {
  __shared__ float smem[64 * 130];
  char* lds = (char*)smem;
  float (*S64)[130] = (float(*)[130])smem;

  const int tid = threadIdx.x;
  const int lane = tid & 63;
  const int wave = tid >> 6;
  const int wx = wave & 1, wy = wave >> 1;
  const int n0 = blockIdx.y * BN;
  const int chunk = blockIdx.x;

  float ts[KNN];
  int ti_[KNN];
#pragma unroll
  for (int q = 0; q < KNN; ++q) { ts[q] = 3.0e38f; ti_[q] = -1; }

  for (int sub = 0; sub < NSUB; ++sub) {
    const int m0 = (chunk * NSUB + sub) * BM;
    float4v acc[4][4];
#pragma unroll
    for (int i = 0; i < 4; ++i)
#pragma unroll
      for (int j = 0; j < 4; ++j) acc[i][j] = (float4v)(0.0f);

    for (int k0 = 0; k0 < D; k0 += BK) {
      __syncthreads();
#pragma unroll
      for (int r = 0; r < 4; ++r) {
        const int id = tid + (r << 8);
        const int n = id >> 3;
        const int c4 = id & 7;
        const int k = c4 << 2;
        const int off = ((n >> 4) << 10) + (((n & 15) | ((k >> 3) << 4)) << 4) +
                        ((c4 & 1) << 3);
        {
          const float4 v = *(const float4*)(Ag + (size_t)(n0 + n) * D + k0 + k);
          const half2v h01 = __builtin_amdgcn_cvt_pkrtz(v.x, v.y);
          const half2v h23 = __builtin_amdgcn_cvt_pkrtz(v.z, v.w);
          const half2v l01 =
              __builtin_amdgcn_cvt_pkrtz(v.x - (float)h01.x, v.y - (float)h01.y);
          const half2v l23 =
              __builtin_amdgcn_cvt_pkrtz(v.z - (float)h23.x, v.w - (float)h23.y);
          union { half2v h[2]; uint2 u; } hh, ll;
          hh.h[0] = h01; hh.h[1] = h23;
          ll.h[0] = l01; ll.h[1] = l23;
          *(uint2*)(lds + off) = hh.u;
          *(uint2*)(lds + 8192 + off) = ll.u;
        }
        {
          const float4 v = *(const float4*)(Bg + (size_t)(m0 + n) * D + k0 + k);
          const half2v h01 = __builtin_amdgcn_cvt_pkrtz(v.x, v.y);
          const half2v h23 = __builtin_amdgcn_cvt_pkrtz(v.z, v.w);
          const half2v l01 =
              __builtin_amdgcn_cvt_pkrtz(v.x - (float)h01.x, v.y - (float)h01.y);
          const half2v l23 =
              __builtin_amdgcn_cvt_pkrtz(v.z - (float)h23.x, v.w - (float)h23.y);
          union { half2v h[2]; uint2 u; } hh, ll;
          hh.h[0] = h01; hh.h[1] = h23;
          ll.h[0] = l01; ll.h[1] = l23;
          *(uint2*)(lds + 16384 + off) = hh.u;
          *(uint2*)(lds + 24576 + off) = ll.u;
        }
      }
      __syncthreads();
      half8 ah[4], al[4], bh[4], bl[4];
#pragma unroll
      for (int t = 0; t < 4; ++t) {
        const int ao = ((((wy << 2) + t) << 10)) + (lane << 4);
        ah[t] = *(half8*)(lds + ao);
        al[t] = *(half8*)(lds + 8192 + ao);
        const int bo = ((((wx << 2) + t) << 10)) + (lane << 4);
        bh[t] = *(half8*)(lds + 16384 + bo);
        bl[t] = *(half8*)(lds + 24576 + bo);
      }
#pragma unroll
      for (int i = 0; i < 4; ++i)
#pragma unroll
        for (int j = 0; j < 4; ++j) {
          acc[i][j] = __builtin_amdgcn_mfma_f32_16x16x32_f16(ah[i], bh[j], acc[i][j], 0, 0, 0);
          acc[i][j] = __builtin_amdgcn_mfma_f32_16x16x32_f16(ah[i], bl[j], acc[i][j], 0, 0, 0);
          acc[i][j] = __builtin_amdgcn_mfma_f32_16x16x32_f16(al[i], bh[j], acc[i][j], 0, 0, 0);
        }
    }

    float b2v[4];
#pragma unroll
    for (int j = 0; j < 4; ++j)
      b2v[j] = b2g[m0 + (wx << 6) + (j << 4) + (lane & 15)];

    for (int p = 0; p < 2; ++p) {
      __syncthreads();
      if (wy == p) {
#pragma unroll
        for (int i = 0; i < 4; ++i)
#pragma unroll
          for (int j = 0; j < 4; ++j)
#pragma unroll
            for (int r = 0; r < 4; ++r)
              S64[(i << 4) + ((lane >> 4) << 2) + r]
                 [(wx << 6) + (j << 4) + (lane & 15)] =
                  fmaf(-2.0f, acc[i][j][r], b2v[j]);
      }
      __syncthreads();
      const int rr = tid & 127;
      if ((rr >> 6) == p) {
        const int lr = rr & 63;
        const int cbase = (tid >> 7) << 6;
        float cut = ts[KNN - 1];
        for (int c = 0; c < 64; ++c) {
          const float s = S64[lr][cbase + c];
          if (s < cut) {
            float cs = s;
            int ci = m0 + cbase + c;
#pragma unroll
            for (int q = 0; q < KNN; ++q) {
              if (cs < ts[q]) {
                const float tf = ts[q]; ts[q] = cs; cs = tf;
                const int tv = ti_[q]; ti_[q] = ci; ci = tv;
              }
            }
            cut = ts[KNN - 1];
          }
        }
      }
    }
  }

  __syncthreads();
  const int r = tid & 127, h = tid >> 7;
  float* mg = (float*)smem;
  if (h == 1) {
#pragma unroll
    for (int q = 0; q < KNN; ++q) {
      mg[r * 20 + q] = ts[q];
      ((int*)mg)[r * 20 + 10 + q] = ti_[q];
    }
  }
  __syncthreads();
  if (h == 0) {
#pragma unroll
    for (int q = 0; q < KNN; ++q) {
      const float s = mg[r * 20 + q];
      const int idx = ((int*)mg)[r * 20 + 10 + q];
      if (s < ts[KNN - 1]) {
        float cs = s;
        int ci = idx;
#pragma unroll
        for (int u = 0; u < KNN; ++u) {
          if (cs < ts[u]) {
            const float tf = ts[u]; ts[u] = cs; cs = tf;
            const int tv = ti_[u]; ti_[u] = ci; ci = tv;
          }
        }
      }
    }
    const size_t base = ((size_t)(n0 + r) * NCHUNK + chunk) * KNN;
#pragma unroll
    for (int q = 0; q < KNN; ++q) {
      cand_s[base + q] = ts[q];
      cand_i[base + q] = ti_[q];
    }
  }
}

// ---------------- phase 2: global top-10 merge + probs mean + argmax ----------------
__global__ __launch_bounds__(256) void knn_finalize_kernel(
    const float* __restrict__ cand_s, const int* __restrict__ cand_i,
    const float* __restrict__ probs, float* __restrict__ out) {
  const int n = blockIdx.x, t = threadIdx.x;
  const size_t cb = (size_t)n * CAND_PER_N;

  float sc[5];
  int id_[5];
#pragma unroll
  for (int r = 0; r < 5; ++r) {
    sc[r] = cand_s[cb + t + (r << 8)];
    id_[r] = cand_i[cb + t + (r << 8)];
  }

  __shared__ float rs[4];
  __shared__ int rm[4];
  __shared__ int win[KNN];

  for (int round = 0; round < KNN; ++round) {
    float bs = 3.0e38f;
    int bm = 0x7fffffff;
#pragma unroll
    for (int r = 0; r < 5; ++r) {
      const bool better =
          (id_[r] >= 0) && (sc[r] < bs || (sc[r] == bs && id_[r] < bm));
      if (better) { bs = sc[r]; bm = id_[r]; }
    }
#pragma unroll
    for (int off = 32; off >= 1; off >>= 1) {
      const float os = __shfl_down(bs, off);
      const int om = __shfl_down(bm, off);
      if (os < bs || (os == bs && om < bm)) { bs = os; bm = om; }
    }
    if ((t & 63) == 0) { rs[t >> 6] = bs; rm[t >> 6] = bm; }
    __syncthreads();
    if (t == 0) {
      float fb = rs[0]; int fm = rm[0];
      for (int w = 1; w < 4; ++w)
        if (rs[w] < fb || (rs[w] == fb && rm[w] < fm)) { fb = rs[w]; fm = rm[w]; }
      win[round] = fm;
    }
    __syncthreads();
    const int wmv = win[round];
#pragma unroll
    for (int r = 0; r < 5; ++r)
      if (id_[r] == wmv) id_[r] = -1;  // m indices are globally unique
  }

  __shared__ float pv[128];
  float myp = -1.0e30f;
  if (t < C) {
    float acc = 0.0f;
#pragma unroll
    for (int q = 0; q < KNN; ++q) acc += probs[(size_t)win[q] * C + t];
    myp = acc * (1.0f / KNN);
    out[N + (size_t)n * C + t] = myp;
  }
  if (t < 128) pv[t] = myp;
  __syncthreads();
  if (t == 0) {
    float bv = pv[0];
    int bi = 0;
    for (int c = 1; c < C; ++c)
      if (pv[c] > bv) { bv = pv[c]; bi = c; }
    out[n] = (float)bi;
  }
}

extern "C" void kernel_launch(void* const* d_in, const int* in_sizes, int n_in,
                              void* d_out, int out_size, void* d_ws, size_t ws_size,
                              hipStream_t stream) {
  const float* features = (const float*)d_in[0];  // (N, D)
  const float* bank = (const float*)d_in[1];      // (M, D)
  const float* probs = (const float*)d_in[2];     // (M, C)
  float* out = (float*)d_out;                     // [labels(N) | probs(N*C)]

  // ws layout (fast path):
  // b2 (0.5 MB) | cand_s (10.5 MB) | cand_i (10.5 MB) | Ahi,Alo (1 MB ea) | Bhi,Blo (64 MB ea)
  float* b2 = (float*)d_ws;
  float* cand_s = b2 + M;
  int* cand_i = (int*)(cand_s + (size_t)N * CAND_PER_N);
  char* Ahi = (char*)(cand_i + (size_t)N * CAND_PER_N);
  char* Alo = Ahi + (size_t)N * D * 2;
  char* Bhi = Alo + (size_t)N * D * 2;
  char* Blo = Bhi + (size_t)M * D * 2;
  const size_t NEED_FAST =
      (size_t)M * 4 + (size_t)N * CAND_PER_N * 8 + (size_t)N * D * 4 + (size_t)M * D * 4;

  b2_kernel<<<M / 4, 256, 0, stream>>>(bank, b2);
  if (ws_size >= NEED_FAST) {
    cvt_kernel<<<(N * 32) / 256, 256, 0, stream>>>(features, Ahi, Alo);
    cvt_kernel<<<(M * 32) / 256, 256, 0, stream>>>(bank, Bhi, Blo);
    knn_chunk_mfma<<<dim3(NCHUNK, N / BN), 256, 0, stream>>>(Ahi, Alo, Bhi, Blo,
                                                             b2, cand_s, cand_i);
  } else {
    knn_chunk_fallback<<<dim3(NCHUNK, N / BN), 256, 0, stream>>>(features, bank,
                                                                 b2, cand_s, cand_i);
  }
  knn_finalize_kernel<<<N, 256, 0, stream>>>(cand_s, cand_i, probs, out);
}

// Round 6
// 1056.266 us; speedup vs baseline: 4.4901x; 1.3346x over previous
//
#include <hip/hip_runtime.h>

#define KNN 10
constexpr int N = 2048;
constexpr int M = 131072;
constexpr int D = 256;
constexpr int C = 126;

constexpr int BN = 128;          // query rows per block
constexpr int BM = 128;          // bank rows per subtile
constexpr int NSUB = 8;          // subtiles per block -> 1024 m per block
constexpr int NCHUNK = M / (BM * NSUB);     // 128 chunks
constexpr int CAND_PER_N = NCHUNK * KNN;    // 1280 candidates per query
constexpr int KSEG = D / 32;                // 8 k-segments per row-group
constexpr int STG = 32768;                  // staging region offset in LDS

typedef __fp16   half2v __attribute__((ext_vector_type(2)));  // cvt_pkrtz result type
typedef _Float16 half8  __attribute__((ext_vector_type(8)));  // MFMA operand type
typedef float   float4v __attribute__((ext_vector_type(4)));

typedef const __attribute__((address_space(1))) void* gas_p;
typedef __attribute__((address_space(3))) void* las_p;

__device__ __forceinline__ void gload_lds16(const void* g, void* l) {
  __builtin_amdgcn_global_load_lds((gas_p)g, (las_p)l, 16, 0, 0);
}

// branch-free sorted-insert chain on 10 scalar (value,index) pairs
#define CHAIN(v, ix)                                                    \
  do {                                                                  \
    const bool c0 = (v) < s0, c1 = (v) < s1, c2 = (v) < s2,             \
               c3 = (v) < s3, c4_ = (v) < s4, c5 = (v) < s5,            \
               c6 = (v) < s6, c7 = (v) < s7, c8 = (v) < s8,             \
               c9 = (v) < s9;                                           \
    s9 = c8 ? s8 : (c9 ? (v) : s9); i9 = c8 ? i8 : (c9 ? (ix) : i9);    \
    s8 = c7 ? s7 : (c8 ? (v) : s8); i8 = c7 ? i7 : (c8 ? (ix) : i8);    \
    s7 = c6 ? s6 : (c7 ? (v) : s7); i7 = c6 ? i6 : (c7 ? (ix) : i7);    \
    s6 = c5 ? s5 : (c6 ? (v) : s6); i6 = c5 ? i5 : (c6 ? (ix) : i6);    \
    s5 = c4_ ? s4 : (c5 ? (v) : s5); i5 = c4_ ? i4 : (c5 ? (ix) : i5);  \
    s4 = c3 ? s3 : (c4_ ? (v) : s4); i4 = c3 ? i3 : (c4_ ? (ix) : i4);  \
    s3 = c2 ? s2 : (c3 ? (v) : s3); i3 = c2 ? i2 : (c3 ? (ix) : i3);    \
    s2 = c1 ? s1 : (c2 ? (v) : s2); i2 = c1 ? i1 : (c2 ? (ix) : i2);    \
    s1 = c0 ? s0 : (c1 ? (v) : s1); i1 = c0 ? i0 : (c1 ? (ix) : i1);    \
    s0 = c0 ? (v) : s0;             i0 = c0 ? (ix) : i0;                \
  } while (0)

// ---------------- phase 0: bank row squared norms ----------------
__global__ __launch_bounds__(256) void b2_kernel(const float* __restrict__ bank,
                                                 float* __restrict__ b2) {
  const int wave = threadIdx.x >> 6, lane = threadIdx.x & 63;
  const int m = (blockIdx.x << 2) + wave;          // 4 rows per block
  const float4 v = ((const float4*)(bank + (size_t)m * D))[lane];  // 64*4 = 256
  float s = v.x * v.x + v.y * v.y + v.z * v.z + v.w * v.w;
#pragma unroll
  for (int off = 32; off >= 1; off >>= 1) s += __shfl_down(s, off);
  if (lane == 0) b2[m] = s;
}

// ---------------- phase 0b: fp32 -> fp16 hi/lo images, MFMA-fragment layout ----
__global__ __launch_bounds__(256) void cvt_kernel(const float* __restrict__ src,
                                                  char* __restrict__ hi,
                                                  char* __restrict__ lo) {
  const int gid = blockIdx.x * 256 + threadIdx.x;
  const int m = gid >> 5, kg = gid & 31;           // kg: 8-element k-group
  const float4 v0 = *(const float4*)(src + (size_t)m * D + (kg << 3));
  const float4 v1 = *(const float4*)(src + (size_t)m * D + (kg << 3) + 4);
  union Pack { half2v h[4]; uint4 u; };
  Pack hh, ll;
  hh.h[0] = __builtin_amdgcn_cvt_pkrtz(v0.x, v0.y);
  hh.h[1] = __builtin_amdgcn_cvt_pkrtz(v0.z, v0.w);
  hh.h[2] = __builtin_amdgcn_cvt_pkrtz(v1.x, v1.y);
  hh.h[3] = __builtin_amdgcn_cvt_pkrtz(v1.z, v1.w);
  ll.h[0] = __builtin_amdgcn_cvt_pkrtz(v0.x - (float)hh.h[0].x, v0.y - (float)hh.h[0].y);
  ll.h[1] = __builtin_amdgcn_cvt_pkrtz(v0.z - (float)hh.h[1].x, v0.w - (float)hh.h[1].y);
  ll.h[2] = __builtin_amdgcn_cvt_pkrtz(v1.x - (float)hh.h[2].x, v1.y - (float)hh.h[2].y);
  ll.h[3] = __builtin_amdgcn_cvt_pkrtz(v1.z - (float)hh.h[3].x, v1.w - (float)hh.h[3].y);
  const size_t off = (((size_t)(m >> 4) * KSEG + (kg >> 2)) << 10) +
                     (((m & 15) | ((kg & 3) << 4)) << 4);
  *(uint4*)(hi + off) = hh.u;
  *(uint4*)(lo + off) = ll.u;
}

// ---------------- phase 1 (fast): pipelined DMA MFMA GEMM + per-chunk top-10 ---
// LDS: [0,32K) XOR-swizzled 64x128 fp32 score tile (+final merge scratch)
//      [32K,64K) staging: Ah 8K | Al 8K | Bh 8K | Bl 8K
__global__ __launch_bounds__(256, 2) void knn_chunk_mfma(
    const char* __restrict__ pAhi, const char* __restrict__ pAlo,
    const char* __restrict__ pBhi, const char* __restrict__ pBlo,
    const float* __restrict__ b2g, float* __restrict__ cand_s,
    int* __restrict__ cand_i) {
  __shared__ char smem[65536];
  float* score = (float*)smem;
  char* stg = smem + STG;

  const int tid = threadIdx.x;
  const int lane = tid & 63;
  const int wave = tid >> 6;
  const int wx = wave & 1, wy = wave >> 1;   // 2x2 wave grid, 64x64 per wave
  const int n0 = blockIdx.y * BN;
  const int chunk = blockIdx.x;
  const int ag0 = n0 >> 4;                   // A row-group base

  float s0 = 3e38f, s1 = 3e38f, s2 = 3e38f, s3 = 3e38f, s4 = 3e38f,
        s5 = 3e38f, s6 = 3e38f, s7 = 3e38f, s8 = 3e38f, s9 = 3e38f;
  int i0 = -1, i1 = -1, i2 = -1, i3 = -1, i4 = -1,
      i5 = -1, i6 = -1, i7 = -1, i8 = -1, i9 = -1;

  auto stage = [&](int bg0, int kseg) {
#pragma unroll
    for (int t = 0; t < 2; ++t) {
      const int grp = (wave << 1) + t;       // 0..7
      const size_t aoff = (((size_t)(ag0 + grp) * KSEG + kseg) << 10) + (lane << 4);
      const size_t boff = (((size_t)(bg0 + grp) * KSEG + kseg) << 10) + (lane << 4);
      const int ldst = (grp << 10) + (lane << 4);
      gload_lds16(pAhi + aoff, stg + ldst);
      gload_lds16(pAlo + aoff, stg + 8192 + ldst);
      gload_lds16(pBhi + boff, stg + 16384 + ldst);
      gload_lds16(pBlo + boff, stg + 24576 + ldst);
    }
  };

  // bootstrap: stage sub 0 / k-seg 0
  stage((chunk * NSUB) * BM >> 4, 0);

  for (int sub = 0; sub < NSUB; ++sub) {
    const int m0 = (chunk * NSUB + sub) * BM;
    const int bg0 = m0 >> 4;
    float4v acc[4][4];
#pragma unroll
    for (int i = 0; i < 4; ++i)
#pragma unroll
      for (int j = 0; j < 4; ++j) acc[i][j] = (float4v)(0.0f);

    for (int k = 0; k < KSEG; ++k) {
      __syncthreads();                       // staged seg k visible (drains DMA)
      half8 ah[4], al[4], bh[4], bl[4];
#pragma unroll
      for (int t = 0; t < 4; ++t) {
        const int ao = (((wy << 2) + t) << 10) + (lane << 4);
        ah[t] = *(half8*)(stg + ao);
        al[t] = *(half8*)(stg + 8192 + ao);
        const int bo = (((wx << 2) + t) << 10) + (lane << 4);
        bh[t] = *(half8*)(stg + 16384 + bo);
        bl[t] = *(half8*)(stg + 24576 + bo);
      }
      __syncthreads();                       // fragments consumed, staging free
      if (k < KSEG - 1) stage(bg0, k + 1);   // DMA flies under the MFMAs
      else if (sub < NSUB - 1) stage(bg0 + 8, 0);  // hidden under score phase
#pragma unroll
      for (int i = 0; i < 4; ++i)
#pragma unroll
        for (int j = 0; j < 4; ++j) {
          acc[i][j] = __builtin_amdgcn_mfma_f32_16x16x32_f16(ah[i], bh[j], acc[i][j], 0, 0, 0);
          acc[i][j] = __builtin_amdgcn_mfma_f32_16x16x32_f16(ah[i], bl[j], acc[i][j], 0, 0, 0);
          acc[i][j] = __builtin_amdgcn_mfma_f32_16x16x32_f16(al[i], bh[j], acc[i][j], 0, 0, 0);
        }
    }

    float b2v[4];
#pragma unroll
    for (int j = 0; j < 4; ++j)
      b2v[j] = b2g[m0 + (wx << 6) + (j << 4) + (lane & 15)];

    // two passes: score rows 0..63 (waves wy==0) then 64..127 (wy==1)
    for (int p = 0; p < 2; ++p) {
      __syncthreads();
      if (wy == p) {
        // C/D layout: col=lane&15, row=(lane>>4)*4+reg  [m89]
#pragma unroll
        for (int i = 0; i < 4; ++i)
#pragma unroll
          for (int j = 0; j < 4; ++j) {
            const int colw = (wx << 6) + (j << 4) + (lane & 15);
#pragma unroll
            for (int r = 0; r < 4; ++r) {
              const int row = (i << 4) + ((lane >> 4) << 2) + r;
              score[(row << 7) + ((((colw >> 2) ^ (row & 31)) << 2) | (colw & 3))] =
                  fmaf(-2.0f, acc[i][j][r], b2v[j]);
            }
          }
      }
      __syncthreads();
      const int rr = tid & 127;
      if ((rr >> 6) == p) {                  // wave-uniform (waves 0,2 / 1,3)
        const int lr = rr & 63;
        const int cbase = (tid >> 7) << 6;   // half-row per scanner
        const float* srow = score + (lr << 7);
        const int key = lr & 31;
        const int cb4 = cbase >> 2;
#pragma unroll 4
        for (int g = 0; g < 16; ++g) {
          const float4 v = *(const float4*)(srow + (((cb4 + g) ^ key) << 2));
          const int ib = m0 + cbase + (g << 2);
          if (v.x < s9) CHAIN(v.x, ib);
          if (v.y < s9) CHAIN(v.y, ib + 1);
          if (v.z < s9) CHAIN(v.z, ib + 2);
          if (v.w < s9) CHAIN(v.w, ib + 3);
        }
      }
    }
  }

  // merge the two half-row scanners, write 10 candidates per row
  __syncthreads();
  const int r = tid & 127, h = tid >> 7;
  float* mg = (float*)smem;
  if (h == 1) {
    float* p_ = mg + r * 20;
    p_[0] = s0; p_[1] = s1; p_[2] = s2; p_[3] = s3; p_[4] = s4;
    p_[5] = s5; p_[6] = s6; p_[7] = s7; p_[8] = s8; p_[9] = s9;
    int* q_ = (int*)(p_ + 10);
    q_[0] = i0; q_[1] = i1; q_[2] = i2; q_[3] = i3; q_[4] = i4;
    q_[5] = i5; q_[6] = i6; q_[7] = i7; q_[8] = i8; q_[9] = i9;
  }
  __syncthreads();
  if (h == 0) {
    const float* p_ = mg + r * 20;
    const int* q_ = (const int*)(p_ + 10);
#pragma unroll
    for (int q = 0; q < KNN; ++q) {
      const float v = p_[q];
      const int ix = q_[q];
      if (v < s9) CHAIN(v, ix);
    }
    const size_t base = ((size_t)(n0 + r) * NCHUNK + chunk) * KNN;
    cand_s[base + 0] = s0; cand_s[base + 1] = s1; cand_s[base + 2] = s2;
    cand_s[base + 3] = s3; cand_s[base + 4] = s4; cand_s[base + 5] = s5;
    cand_s[base + 6] = s6; cand_s[base + 7] = s7; cand_s[base + 8] = s8;
    cand_s[base + 9] = s9;
    cand_i[base + 0] = i0; cand_i[base + 1] = i1; cand_i[base + 2] = i2;
    cand_i[base + 3] = i3; cand_i[base + 4] = i4; cand_i[base + 5] = i5;
    cand_i[base + 6] = i6; cand_i[base + 7] = i7; cand_i[base + 8] = i8;
    cand_i[base + 9] = i9;
  }
}

// ---------------- phase 1 (fallback, round-3 proven): in-kernel conversion ----
__global__ __launch_bounds__(256, 2) void knn_chunk_fallback(
    const float* __restrict__ Ag, const float* __restrict__ Bg,
    const float* __restrict__ b2g, float* __restrict__ cand_s,
    int* __restrict__ cand_i) {
  __shared__ float smemf[64 * 130];
  char* lds = (char*)smemf;
  float (*S64)[130] = (float(*)[130])smemf;

  const int tid = threadIdx.x;
  const int lane = tid & 63;
  const int wave = tid >> 6;
  const int wx = wave & 1, wy = wave >> 1;
  const int n0 = blockIdx.y * BN;
  const int chunk = blockIdx.x;

  float ts[KNN];
  int ti_[KNN];
#pragma unroll
  for (int q = 0; q < KNN; ++q) { ts[q] = 3.0e38f; ti_[q] = -1; }

  for (int sub = 0; sub < NSUB; ++sub) {
    const int m0 = (chunk * NSUB + sub) * BM;
    float4v acc[4][4];
#pragma unroll
    for (int i = 0; i < 4; ++i)
#pragma unroll
      for (int j = 0; j < 4; ++j) acc[i][j] = (float4v)(0.0f);

    for (int k0 = 0; k0 < D; k0 += 32) {
      __syncthreads();
#pragma unroll
      for (int r = 0; r < 4; ++r) {
        const int id = tid + (r << 8);
        const int n = id >> 3;
        const int c4 = id & 7;
        const int k = c4 << 2;
        const int off = ((n >> 4) << 10) + (((n & 15) | ((k >> 3) << 4)) << 4) +
                        ((c4 & 1) << 3);
        {
          const float4 v = *(const float4*)(Ag + (size_t)(n0 + n) * D + k0 + k);
          const half2v h01 = __builtin_amdgcn_cvt_pkrtz(v.x, v.y);
          const half2v h23 = __builtin_amdgcn_cvt_pkrtz(v.z, v.w);
          const half2v l01 =
              __builtin_amdgcn_cvt_pkrtz(v.x - (float)h01.x, v.y - (float)h01.y);
          const half2v l23 =
              __builtin_amdgcn_cvt_pkrtz(v.z - (float)h23.x, v.w - (float)h23.y);
          union { half2v h[2]; uint2 u; } hh, ll;
          hh.h[0] = h01; hh.h[1] = h23;
          ll.h[0] = l01; ll.h[1] = l23;
          *(uint2*)(lds + off) = hh.u;
          *(uint2*)(lds + 8192 + off) = ll.u;
        }
        {
          const float4 v = *(const float4*)(Bg + (size_t)(m0 + n) * D + k0 + k);
          const half2v h01 = __builtin_amdgcn_cvt_pkrtz(v.x, v.y);
          const half2v h23 = __builtin_amdgcn_cvt_pkrtz(v.z, v.w);
          const half2v l01 =
              __builtin_amdgcn_cvt_pkrtz(v.x - (float)h01.x, v.y - (float)h01.y);
          const half2v l23 =
              __builtin_amdgcn_cvt_pkrtz(v.z - (float)h23.x, v.w - (float)h23.y);
          union { half2v h[2]; uint2 u; } hh, ll;
          hh.h[0] = h01; hh.h[1] = h23;
          ll.h[0] = l01; ll.h[1] = l23;
          *(uint2*)(lds + 16384 + off) = hh.u;
          *(uint2*)(lds + 24576 + off) = ll.u;
        }
      }
      __syncthreads();
      half8 ah[4], al[4], bh[4], bl[4];
#pragma unroll
      for (int t = 0; t < 4; ++t) {
        const int ao = ((((wy << 2) + t) << 10)) + (lane << 4);
        ah[t] = *(half8*)(lds + ao);
        al[t] = *(half8*)(lds + 8192 + ao);
        const int bo = ((((wx << 2) + t) << 10)) + (lane << 4);
        bh[t] = *(half8*)(lds + 16384 + bo);
        bl[t] = *(half8*)(lds + 24576 + bo);
      }
#pragma unroll
      for (int i = 0; i < 4; ++i)
#pragma unroll
        for (int j = 0; j < 4; ++j) {
          acc[i][j] = __builtin_amdgcn_mfma_f32_16x16x32_f16(ah[i], bh[j], acc[i][j], 0, 0, 0);
          acc[i][j] = __builtin_amdgcn_mfma_f32_16x16x32_f16(ah[i], bl[j], acc[i][j], 0, 0, 0);
          acc[i][j] = __builtin_amdgcn_mfma_f32_16x16x32_f16(al[i], bh[j], acc[i][j], 0, 0, 0);
        }
    }

    float b2v[4];
#pragma unroll
    for (int j = 0; j < 4; ++j)
      b2v[j] = b2g[m0 + (wx << 6) + (j << 4) + (lane & 15)];

    for (int p = 0; p < 2; ++p) {
      __syncthreads();
      if (wy == p) {
#pragma unroll
        for (int i = 0; i < 4; ++i)
#pragma unroll
          for (int j = 0; j < 4; ++j)
#pragma unroll
            for (int r = 0; r < 4; ++r)
              S64[(i << 4) + ((lane >> 4) << 2) + r]
                 [(wx << 6) + (j << 4) + (lane & 15)] =
                  fmaf(-2.0f, acc[i][j][r], b2v[j]);
      }
      __syncthreads();
      const int rr = tid & 127;
      if ((rr >> 6) == p) {
        const int lr = rr & 63;
        const int cbase = (tid >> 7) << 6;
        float cut = ts[KNN - 1];
        for (int c = 0; c < 64; ++c) {
          const float s = S64[lr][cbase + c];
          if (s < cut) {
            float cs = s;
            int ci = m0 + cbase + c;
#pragma unroll
            for (int q = 0; q < KNN; ++q) {
              if (cs < ts[q]) {
                const float tf = ts[q]; ts[q] = cs; cs = tf;
                const int tv = ti_[q]; ti_[q] = ci; ci = tv;
              }
            }
            cut = ts[KNN - 1];
          }
        }
      }
    }
  }

  __syncthreads();
  const int r = tid & 127, h = tid >> 7;
  float* mg = (float*)smemf;
  if (h == 1) {
#pragma unroll
    for (int q = 0; q < KNN; ++q) {
      mg[r * 20 + q] = ts[q];
      ((int*)mg)[r * 20 + 10 + q] = ti_[q];
    }
  }
  __syncthreads();
  if (h == 0) {
#pragma unroll
    for (int q = 0; q < KNN; ++q) {
      const float s = mg[r * 20 + q];
      const int idx = ((int*)mg)[r * 20 + 10 + q];
      if (s < ts[KNN - 1]) {
        float cs = s;
        int ci = idx;
#pragma unroll
        for (int u = 0; u < KNN; ++u) {
          if (cs < ts[u]) {
            const float tf = ts[u]; ts[u] = cs; cs = tf;
            const int tv = ti_[u]; ti_[u] = ci; ci = tv;
          }
        }
      }
    }
    const size_t base = ((size_t)(n0 + r) * NCHUNK + chunk) * KNN;
#pragma unroll
    for (int q = 0; q < KNN; ++q) {
      cand_s[base + q] = ts[q];
      cand_i[base + q] = ti_[q];
    }
  }
}

// ---------------- phase 2: global top-10 merge + probs mean + argmax ----------------
__global__ __launch_bounds__(256) void knn_finalize_kernel(
    const float* __restrict__ cand_s, const int* __restrict__ cand_i,
    const float* __restrict__ probs, float* __restrict__ out) {
  const int n = blockIdx.x, t = threadIdx.x;
  const size_t cb = (size_t)n * CAND_PER_N;

  float sc[5];
  int id_[5];
#pragma unroll
  for (int r = 0; r < 5; ++r) {
    sc[r] = cand_s[cb + t + (r << 8)];
    id_[r] = cand_i[cb + t + (r << 8)];
  }

  __shared__ float rs[4];
  __shared__ int rm[4];
  __shared__ int win[KNN];

  for (int round = 0; round < KNN; ++round) {
    float bs = 3.0e38f;
    int bm = 0x7fffffff;
#pragma unroll
    for (int r = 0; r < 5; ++r) {
      const bool better =
          (id_[r] >= 0) && (sc[r] < bs || (sc[r] == bs && id_[r] < bm));
      if (better) { bs = sc[r]; bm = id_[r]; }
    }
#pragma unroll
    for (int off = 32; off >= 1; off >>= 1) {
      const float os = __shfl_down(bs, off);
      const int om = __shfl_down(bm, off);
      if (os < bs || (os == bs && om < bm)) { bs = os; bm = om; }
    }
    if ((t & 63) == 0) { rs[t >> 6] = bs; rm[t >> 6] = bm; }
    __syncthreads();
    if (t == 0) {
      float fb = rs[0]; int fm = rm[0];
      for (int w = 1; w < 4; ++w)
        if (rs[w] < fb || (rs[w] == fb && rm[w] < fm)) { fb = rs[w]; fm = rm[w]; }
      win[round] = fm;
    }
    __syncthreads();
    const int wmv = win[round];
#pragma unroll
    for (int r = 0; r < 5; ++r)
      if (id_[r] == wmv) id_[r] = -1;  // m indices are globally unique
  }

  __shared__ float pv[128];
  float myp = -1.0e30f;
  if (t < C) {
    float acc = 0.0f;
#pragma unroll
    for (int q = 0; q < KNN; ++q) acc += probs[(size_t)win[q] * C + t];
    myp = acc * (1.0f / KNN);
    out[N + (size_t)n * C + t] = myp;
  }
  if (t < 128) pv[t] = myp;
  __syncthreads();
  if (t == 0) {
    float bv = pv[0];
    int bi = 0;
    for (int c = 1; c < C; ++c)
      if (pv[c] > bv) { bv = pv[c]; bi = c; }
    out[n] = (float)bi;
  }
}

extern "C" void kernel_launch(void* const* d_in, const int* in_sizes, int n_in,
                              void* d_out, int out_size, void* d_ws, size_t ws_size,
                              hipStream_t stream) {
  const float* features = (const float*)d_in[0];  // (N, D)
  const float* bank = (const float*)d_in[1];      // (M, D)
  const float* probs = (const float*)d_in[2];     // (M, C)
  float* out = (float*)d_out;                     // [labels(N) | probs(N*C)]

  // ws layout (fast path):
  // b2 (0.5 MB) | cand_s (10.5 MB) | cand_i (10.5 MB) | Ahi,Alo (1 MB ea) | Bhi,Blo (64 MB ea)
  float* b2 = (float*)d_ws;
  float* cand_s = b2 + M;
  int* cand_i = (int*)(cand_s + (size_t)N * CAND_PER_N);
  char* Ahi = (char*)(cand_i + (size_t)N * CAND_PER_N);
  char* Alo = Ahi + (size_t)N * D * 2;
  char* Bhi = Alo + (size_t)N * D * 2;
  char* Blo = Bhi + (size_t)M * D * 2;
  const size_t NEED_FAST =
      (size_t)M * 4 + (size_t)N * CAND_PER_N * 8 + (size_t)N * D * 4 + (size_t)M * D * 4;

  b2_kernel<<<M / 4, 256, 0, stream>>>(bank, b2);
  if (ws_size >= NEED_FAST) {
    cvt_kernel<<<(N * 32) / 256, 256, 0, stream>>>(features, Ahi, Alo);
    cvt_kernel<<<(M * 32) / 256, 256, 0, stream>>>(bank, Bhi, Blo);
    knn_chunk_mfma<<<dim3(NCHUNK, N / BN), 256, 0, stream>>>(Ahi, Alo, Bhi, Blo,
                                                             b2, cand_s, cand_i);
  } else {
    knn_chunk_fallback<<<dim3(NCHUNK, N / BN), 256, 0, stream>>>(features, bank,
                                                                 b2, cand_s, cand_i);
  }
  knn_finalize_kernel<<<N, 256, 0, stream>>>(cand_s, cand_i, probs, out);
}